// Round 3
// baseline (2342.539 us; speedup 1.0000x reference)
//
#include <hip/hip_runtime.h>

namespace {
constexpr int B_     = 8;
constexpr int NT_    = 256;
constexpr int NZ_    = 256;
constexpr int NX_    = 256;
constexpr int NREC_  = 64;
constexpr int PIECES = 8;              // vertical strips per batch
constexpr int IROWS  = NZ_ / PIECES;   // 32 interior rows per strip
constexpr int G      = 16;             // ghost width = steps per round
constexpr int ROUNDS = NT_ / G;        // 16
constexpr float DT2  = 1e-6f;          // DT*DT
constexpr float KLAP = 1e-8f;          // DT*DT/(DH*DH)
constexpr size_t FLAGS_BYTES = 4096;

// 3-level cndmask tree: h[idx] for runtime idx in [0,8)
__device__ __forceinline__ float select8(const float (&h)[8], int idx) {
    float a0 = (idx & 1) ? h[1] : h[0];
    float a1 = (idx & 1) ? h[3] : h[2];
    float a2 = (idx & 1) ? h[5] : h[4];
    float a3 = (idx & 1) ? h[7] : h[6];
    float b0 = (idx & 2) ? a1 : a0;
    float b1 = (idx & 2) ? a3 : a2;
    return (idx & 4) ? b1 : b0;
}

__device__ __forceinline__ void st_agent(float* p, float v) {
    __hip_atomic_store(p, v, __ATOMIC_RELAXED, __HIP_MEMORY_SCOPE_AGENT);
}
__device__ __forceinline__ float ld_agent(const float* p) {
    return __hip_atomic_load(p, __ATOMIC_RELAXED, __HIP_MEMORY_SCOPE_AGENT);
}
} // namespace

// 64 blocks: piece p of batch b, blockIdx = p*8 + b (pieces of a batch share an
// XCD under round-robin dispatch — perf heuristic only). Each block evolves an
// EXTENDED region of 64 rows (32 interior + 16 ghost each side); ghosts are
// recomputed redundantly so cross-block exchange happens only every G=16 steps.
// Thread owns 2 ext rows x 8 cols in registers. Dirichlet + out-of-domain cells
// get cf=0 (stay exactly 0). Intra-block vertical halo: LDS + shfl_xor(32).
extern "C" __global__ __launch_bounds__(1024, 4)
void wave_tb_kernel(const float* __restrict__ x,
                    const float* __restrict__ vp,
                    const int* __restrict__ src_loc,
                    const int* __restrict__ rec_loc,
                    float* __restrict__ out,
                    int* __restrict__ flags,   // [64] round counters
                    float* __restrict__ gbuf)  // [buf2][64][side2][lvl2][G][256]
{
    __shared__ float pub[32][NX_];   // 32 KB: one published row per thread
    __shared__ float wav[NT_];       // 1 KB wavelet

    const int bid = blockIdx.x;
    const int b   = bid & 7;
    const int p   = bid >> 3;
    const int blk = b * PIECES + p;
    const int tid = threadIdx.x;
    const int tx  = tid & 31;          // col group (8 cols)
    const int ty  = tid >> 5;          // ext-row pair index 0..31
    const int gc0 = tx << 3;
    const int gr0 = p * IROWS - G + 2 * ty;   // global row of er0 (may be <0/>255)
    const int gr1 = gr0 + 1;

    if (tid < NT_) wav[tid] = x[b * NT_ + tid];

    // cf = vp^2*DT^2/DH^2, zeroed at Dirichlet boundary + out-of-domain rows.
    float cf[2][8];
#pragma unroll
    for (int r = 0; r < 2; ++r) {
        int gr = gr0 + r;
        int crow = gr < 0 ? 0 : (gr > 255 ? 255 : gr);
        bool rowok = (gr >= 1) && (gr <= 254);
        const float4* v4 = (const float4*)&vp[crow * NX_ + gc0];
        float4 q0 = v4[0], q1 = v4[1];
        float vv[8] = {q0.x,q0.y,q0.z,q0.w,q1.x,q1.y,q1.z,q1.w};
#pragma unroll
        for (int j = 0; j < 8; ++j) {
            bool colok = !((tx == 0 && j == 0) || (tx == 31 && j == 7));
            cf[r][j] = (rowok && colok) ? vv[j] * vv[j] * KLAP : 0.0f;
        }
    }

    const int sz = src_loc[b*2+0], sx = src_loc[b*2+1];
    const bool scol = ((sx >> 3) == tx);
    const bool src_r0 = scol && (sz == gr0);
    const bool src_r1 = scol && (sz == gr1);
    const int  sj = sx & 7;

    // receiver ownership: interior rows only (ty in [8,24)), scalar slots
    int rt0 = 0, rt1 = 0, rt2 = 0, rt3 = 0, rcnt = 0;
    const bool interior = (ty >= 8) && (ty < 24);
#pragma unroll 1
    for (int r = 0; r < NREC_; ++r) {
        int rz = rec_loc[(b*NREC_ + r)*2 + 0];
        int rx = rec_loc[(b*NREC_ + r)*2 + 1];
        if (interior && ((rx >> 3) == tx) && (rz == gr0 || rz == gr1)) {
            int pk = (r << 4) | ((rz == gr1) ? 8 : 0) | (rx & 7);
            if      (rcnt == 0) rt0 = pk;
            else if (rcnt == 1) rt1 = pk;
            else if (rcnt == 2) rt2 = pk;
            else if (rcnt == 3) rt3 = pk;
            ++rcnt;
        }
    }

    float hA[2][8], hB[2][8];
#pragma unroll
    for (int r = 0; r < 2; ++r)
#pragma unroll
        for (int j = 0; j < 8; ++j) { hA[r][j] = 0.f; hB[r][j] = 0.f; }

    float* outb = out + b * (NT_ * NREC_);

    auto gslab = [&](int bk, int side, int lvl, int buf) -> float* {
        return gbuf + (size_t)((((buf * 64 + bk) * 2 + side) * 2 + lvl)) * (G * NX_);
    };

    // one leapfrog step: h2 <- update(h1, h2); h2 becomes current
    auto step = [&](float (&h1)[2][8], float (&h2)[2][8], int t) {
        const bool odd = (ty & 1) != 0;
        // publish the row the cross-wave neighbor needs:
        // even ty -> er0 (read by ty-1 as south), odd ty -> er1 (read by ty+1 as north)
        {
            float4 p0, p1;
            if (odd) { p0 = make_float4(h1[1][0],h1[1][1],h1[1][2],h1[1][3]);
                       p1 = make_float4(h1[1][4],h1[1][5],h1[1][6],h1[1][7]); }
            else     { p0 = make_float4(h1[0][0],h1[0][1],h1[0][2],h1[0][3]);
                       p1 = make_float4(h1[0][4],h1[0][5],h1[0][6],h1[0][7]); }
            *(float4*)&pub[ty][gc0]     = p0;
            *(float4*)&pub[ty][gc0 + 4] = p1;
        }
        __syncthreads();

        float nn[8], ss[8];
        {
            int prw = odd ? ty + 1 : ty - 1;
            int prc = prw < 0 ? 0 : (prw > 31 ? 31 : prw);
            bool valid = odd ? (ty < 31) : (ty > 0);
            float4 q0 = *(const float4*)&pub[prc][gc0];
            float4 q1 = *(const float4*)&pub[prc][gc0 + 4];
            float o[8] = {q0.x,q0.y,q0.z,q0.w,q1.x,q1.y,q1.z,q1.w};
#pragma unroll
            for (int j = 0; j < 8; ++j) if (!valid) o[j] = 0.f;
#pragma unroll
            for (int j = 0; j < 8; ++j) {
                float sent = odd ? h1[0][j] : h1[1][j];
                float got  = __shfl_xor(sent, 32, 64);
                nn[j] = odd ? got  : o[j];   // north of er0
                ss[j] = odd ? o[j] : got;    // south of er1
            }
        }

        float wv0 = __shfl_up(h1[0][7], 1, 64);
        float wv1 = __shfl_up(h1[1][7], 1, 64);
        float ev0 = __shfl_down(h1[0][0], 1, 64);
        float ev1 = __shfl_down(h1[1][0], 1, 64);
        float ww0 = (tx == 0)  ? 0.f : wv0;
        float ww1 = (tx == 0)  ? 0.f : wv1;
        float ee0 = (tx == 31) ? 0.f : ev0;
        float ee1 = (tx == 31) ? 0.f : ev1;

        // hn = 2*h1 - h2 + cf*(n+s+w+e - 4*h1)
#pragma unroll
        for (int j = 0; j < 8; ++j) {
            float w0 = (j > 0) ? h1[0][j-1] : ww0;
            float e0 = (j < 7) ? h1[0][j+1] : ee0;
            float sum0 = (nn[j] + h1[1][j]) + (w0 + e0);
            float l0 = fmaf(-4.f, h1[0][j], sum0);
            h2[0][j] = fmaf(cf[0][j], l0, fmaf(2.f, h1[0][j], -h2[0][j]));

            float w1 = (j > 0) ? h1[1][j-1] : ww1;
            float e1 = (j < 7) ? h1[1][j+1] : ee1;
            float sum1 = (h1[0][j] + ss[j]) + (w1 + e1);
            float l1 = fmaf(-4.f, h1[1][j], sum1);
            h2[1][j] = fmaf(cf[1][j], l1, fmaf(2.f, h1[1][j], -h2[1][j]));
        }

        if (src_r0 | src_r1) {
            float v = DT2 * wav[t];
#pragma unroll
            for (int j = 0; j < 8; ++j) if (j == sj) {
                if (src_r0) h2[0][j] += v;
                if (src_r1) h2[1][j] += v;
            }
        }

        if (rcnt > 0) { float v = (rt0 & 8) ? select8(h2[1], rt0 & 7) : select8(h2[0], rt0 & 7);
                        outb[t*NREC_ + (rt0 >> 4)] = v; }
        if (rcnt > 1) { float v = (rt1 & 8) ? select8(h2[1], rt1 & 7) : select8(h2[0], rt1 & 7);
                        outb[t*NREC_ + (rt1 >> 4)] = v; }
        if (rcnt > 2) { float v = (rt2 & 8) ? select8(h2[1], rt2 & 7) : select8(h2[0], rt2 & 7);
                        outb[t*NREC_ + (rt2 >> 4)] = v; }
        if (rcnt > 3) { float v = (rt3 & 8) ? select8(h2[1], rt3 & 7) : select8(h2[0], rt3 & 7);
                        outb[t*NREC_ + (rt3 >> 4)] = v; }

        __syncthreads();   // protect pub (WAR) for next step
    };

    // ghost exchange after round e: cur/prev are latest two time levels
    auto exchange = [&](float (&cur)[2][8], float (&prev)[2][8], int e) {
        const int buf = e & 1;
        if (ty >= 8 && ty < 24) {          // publish interior boundary slabs
            int side = (ty < 16) ? 0 : 1;
            int sr0 = 2 * ty - (side ? 32 : 16);
            float* d0 = gslab(blk, side, 0, buf) + gc0;
            float* d1 = gslab(blk, side, 1, buf) + gc0;
#pragma unroll
            for (int j = 0; j < 8; ++j) {
                st_agent(&d0[sr0*NX_ + j],       cur[0][j]);
                st_agent(&d0[(sr0+1)*NX_ + j],   cur[1][j]);
                st_agent(&d1[sr0*NX_ + j],       prev[0][j]);
                st_agent(&d1[(sr0+1)*NX_ + j],   prev[1][j]);
            }
        }
        __syncthreads();                   // drains vmcnt: slabs at coherent point
        if (tid == 0) {
            __threadfence();
            __hip_atomic_store(&flags[blk], e + 1, __ATOMIC_RELEASE,
                               __HIP_MEMORY_SCOPE_AGENT);
        }
        if (tid == 0 && p > 0) {
            while (__hip_atomic_load(&flags[blk-1], __ATOMIC_ACQUIRE,
                                     __HIP_MEMORY_SCOPE_AGENT) < e + 1)
                __builtin_amdgcn_s_sleep(2);
        }
        if (tid == 64 && p < PIECES-1) {   // second wave polls south in parallel
            while (__hip_atomic_load(&flags[blk+1], __ATOMIC_ACQUIRE,
                                     __HIP_MEMORY_SCOPE_AGENT) < e + 1)
                __builtin_amdgcn_s_sleep(2);
        }
        __syncthreads();
        if (ty < 8 && p > 0) {             // refill top ghost from north neighbor
            int sr0 = 2 * ty;
            const float* s0 = gslab(blk-1, 1, 0, buf) + gc0;
            const float* s1 = gslab(blk-1, 1, 1, buf) + gc0;
#pragma unroll
            for (int j = 0; j < 8; ++j) {
                cur[0][j]  = ld_agent(&s0[sr0*NX_ + j]);
                cur[1][j]  = ld_agent(&s0[(sr0+1)*NX_ + j]);
                prev[0][j] = ld_agent(&s1[sr0*NX_ + j]);
                prev[1][j] = ld_agent(&s1[(sr0+1)*NX_ + j]);
            }
        }
        if (ty >= 24 && p < PIECES-1) {    // refill bottom ghost from south
            int sr0 = 2 * ty - 48;
            const float* s0 = gslab(blk+1, 0, 0, buf) + gc0;
            const float* s1 = gslab(blk+1, 0, 1, buf) + gc0;
#pragma unroll
            for (int j = 0; j < 8; ++j) {
                cur[0][j]  = ld_agent(&s0[sr0*NX_ + j]);
                cur[1][j]  = ld_agent(&s0[(sr0+1)*NX_ + j]);
                prev[0][j] = ld_agent(&s1[sr0*NX_ + j]);
                prev[1][j] = ld_agent(&s1[(sr0+1)*NX_ + j]);
            }
        }
    };

    int t = 0;
#pragma unroll 1
    for (int e = 0; e < ROUNDS; ++e) {
#pragma unroll 1
        for (int s = 0; s < G; s += 2) {
            step(hA, hB, t);
            step(hB, hA, t + 1);
            t += 2;
        }
        // after 16 steps: hA = current, hB = previous
        if (e < ROUNDS - 1) exchange(hA, hB, e);
    }
}

extern "C" void kernel_launch(void* const* d_in, const int* in_sizes, int n_in,
                              void* d_out, int out_size, void* d_ws, size_t ws_size,
                              hipStream_t stream) {
    const float* x   = (const float*)d_in[0];
    const float* vp  = (const float*)d_in[1];
    const int*   src = (const int*)d_in[2];
    const int*   rec = (const int*)d_in[3];
    float*       o   = (float*)d_out;
    int*   flags = (int*)d_ws;
    float* gbuf  = (float*)((char*)d_ws + FLAGS_BYTES);
    hipMemsetAsync(d_ws, 0, FLAGS_BYTES, stream);   // zero flags (ws is poisoned)
    hipLaunchKernelGGL(wave_tb_kernel, dim3(B_ * PIECES), dim3(1024), 0, stream,
                       x, vp, src, rec, o, flags, gbuf);
}

// Round 4
// 2183.462 us; speedup vs baseline: 1.0729x; 1.0729x over previous
//
#include <hip/hip_runtime.h>
#include <hip/hip_cooperative_groups.h>

namespace cg = cooperative_groups;

namespace {
constexpr int B_     = 8;
constexpr int NT_    = 256;
constexpr int NZ_    = 256;
constexpr int NX_    = 256;
constexpr int NREC_  = 64;
constexpr int PIECES = 8;              // vertical strips per batch
constexpr int IROWS  = NZ_ / PIECES;   // 32 interior rows per strip
constexpr int G      = 16;             // ghost width = steps per round
constexpr int ROUNDS = NT_ / G;        // 16
constexpr float DT2  = 1e-6f;          // DT*DT
constexpr float KLAP = 1e-8f;          // DT*DT/(DH*DH)

// 3-level cndmask tree: h[idx] for runtime idx in [0,8)
__device__ __forceinline__ float select8(const float (&h)[8], int idx) {
    float a0 = (idx & 1) ? h[1] : h[0];
    float a1 = (idx & 1) ? h[3] : h[2];
    float a2 = (idx & 1) ? h[5] : h[4];
    float a3 = (idx & 1) ? h[7] : h[6];
    float b0 = (idx & 2) ? a1 : a0;
    float b1 = (idx & 2) ? a3 : a2;
    return (idx & 4) ? b1 : b0;
}
} // namespace

// 64 cooperative blocks: piece p of batch b, blockIdx = p*8 + b (pieces of a
// batch share an XCD under round-robin dispatch — perf heuristic only; the
// correctness of the exchange rests on grid.sync(), which is dispatch-order
// and XCD agnostic). Each block evolves 64 ext rows (32 interior + 16 ghost
// each side) redundantly; cross-block exchange only every G=16 steps, via
// PLAIN cached float4 slab stores/loads bracketed by grid.sync() (the R3
// lesson: per-dword agent-scope atomic stores write through uncached at
// ~300 GB/s device-wide and dominated the runtime).
extern "C" __global__ __launch_bounds__(1024, 4)
void wave_tb_kernel(const float* __restrict__ x,
                    const float* __restrict__ vp,
                    const int* __restrict__ src_loc,
                    const int* __restrict__ rec_loc,
                    float* __restrict__ out,
                    float* __restrict__ gbuf)  // [buf2][64][side2][lvl2][G][256]
{
    __shared__ float pub[32][NX_];   // 32 KB: one published row per thread
    __shared__ float wav[NT_];       // 1 KB wavelet

    cg::grid_group grid = cg::this_grid();

    const int bid = blockIdx.x;
    const int b   = bid & 7;
    const int p   = bid >> 3;
    const int blk = b * PIECES + p;
    const int tid = threadIdx.x;
    const int tx  = tid & 31;          // col group (8 cols)
    const int ty  = tid >> 5;          // ext-row pair index 0..31
    const int gc0 = tx << 3;
    const int gr0 = p * IROWS - G + 2 * ty;   // global row of er0 (may be <0/>255)
    const int gr1 = gr0 + 1;

    if (tid < NT_) wav[tid] = x[b * NT_ + tid];

    // cf = vp^2*DT^2/DH^2, zeroed at Dirichlet boundary + out-of-domain rows.
    float cf[2][8];
#pragma unroll
    for (int r = 0; r < 2; ++r) {
        int gr = gr0 + r;
        int crow = gr < 0 ? 0 : (gr > 255 ? 255 : gr);
        bool rowok = (gr >= 1) && (gr <= 254);
        const float4* v4 = (const float4*)&vp[crow * NX_ + gc0];
        float4 q0 = v4[0], q1 = v4[1];
        float vv[8] = {q0.x,q0.y,q0.z,q0.w,q1.x,q1.y,q1.z,q1.w};
#pragma unroll
        for (int j = 0; j < 8; ++j) {
            bool colok = !((tx == 0 && j == 0) || (tx == 31 && j == 7));
            cf[r][j] = (rowok && colok) ? vv[j] * vv[j] * KLAP : 0.0f;
        }
    }

    const int sz = src_loc[b*2+0], sx = src_loc[b*2+1];
    const bool scol = ((sx >> 3) == tx);
    const bool src_r0 = scol && (sz == gr0);
    const bool src_r1 = scol && (sz == gr1);
    const int  sj = sx & 7;

    // receiver ownership: interior rows only (ty in [8,24)), scalar slots
    int rt0 = 0, rt1 = 0, rt2 = 0, rt3 = 0, rcnt = 0;
    const bool interior = (ty >= 8) && (ty < 24);
#pragma unroll 1
    for (int r = 0; r < NREC_; ++r) {
        int rz = rec_loc[(b*NREC_ + r)*2 + 0];
        int rx = rec_loc[(b*NREC_ + r)*2 + 1];
        if (interior && ((rx >> 3) == tx) && (rz == gr0 || rz == gr1)) {
            int pk = (r << 4) | ((rz == gr1) ? 8 : 0) | (rx & 7);
            if      (rcnt == 0) rt0 = pk;
            else if (rcnt == 1) rt1 = pk;
            else if (rcnt == 2) rt2 = pk;
            else if (rcnt == 3) rt3 = pk;
            ++rcnt;
        }
    }

    float hA[2][8], hB[2][8];
#pragma unroll
    for (int r = 0; r < 2; ++r)
#pragma unroll
        for (int j = 0; j < 8; ++j) { hA[r][j] = 0.f; hB[r][j] = 0.f; }

    float* outb = out + b * (NT_ * NREC_);

    auto gslab = [&](int bk, int side, int lvl, int buf) -> float* {
        return gbuf + (size_t)((((buf * 64 + bk) * 2 + side) * 2 + lvl)) * (G * NX_);
    };

    // one leapfrog step: h2 <- update(h1, h2); h2 becomes current
    auto step = [&](float (&h1)[2][8], float (&h2)[2][8], int t) {
        const bool odd = (ty & 1) != 0;
        // publish the row the cross-wave neighbor needs:
        // even ty -> er0 (read by ty-1 as south), odd ty -> er1 (read by ty+1 as north)
        {
            float4 p0, p1;
            if (odd) { p0 = make_float4(h1[1][0],h1[1][1],h1[1][2],h1[1][3]);
                       p1 = make_float4(h1[1][4],h1[1][5],h1[1][6],h1[1][7]); }
            else     { p0 = make_float4(h1[0][0],h1[0][1],h1[0][2],h1[0][3]);
                       p1 = make_float4(h1[0][4],h1[0][5],h1[0][6],h1[0][7]); }
            *(float4*)&pub[ty][gc0]     = p0;
            *(float4*)&pub[ty][gc0 + 4] = p1;
        }
        __syncthreads();

        float nn[8], ss[8];
        {
            int prw = odd ? ty + 1 : ty - 1;
            int prc = prw < 0 ? 0 : (prw > 31 ? 31 : prw);
            bool valid = odd ? (ty < 31) : (ty > 0);
            float4 q0 = *(const float4*)&pub[prc][gc0];
            float4 q1 = *(const float4*)&pub[prc][gc0 + 4];
            float o[8] = {q0.x,q0.y,q0.z,q0.w,q1.x,q1.y,q1.z,q1.w};
#pragma unroll
            for (int j = 0; j < 8; ++j) if (!valid) o[j] = 0.f;
#pragma unroll
            for (int j = 0; j < 8; ++j) {
                float sent = odd ? h1[0][j] : h1[1][j];
                float got  = __shfl_xor(sent, 32, 64);
                nn[j] = odd ? got  : o[j];   // north of er0
                ss[j] = odd ? o[j] : got;    // south of er1
            }
        }

        float wv0 = __shfl_up(h1[0][7], 1, 64);
        float wv1 = __shfl_up(h1[1][7], 1, 64);
        float ev0 = __shfl_down(h1[0][0], 1, 64);
        float ev1 = __shfl_down(h1[1][0], 1, 64);
        float ww0 = (tx == 0)  ? 0.f : wv0;
        float ww1 = (tx == 0)  ? 0.f : wv1;
        float ee0 = (tx == 31) ? 0.f : ev0;
        float ee1 = (tx == 31) ? 0.f : ev1;

        // hn = 2*h1 - h2 + cf*(n+s+w+e - 4*h1)
#pragma unroll
        for (int j = 0; j < 8; ++j) {
            float w0 = (j > 0) ? h1[0][j-1] : ww0;
            float e0 = (j < 7) ? h1[0][j+1] : ee0;
            float sum0 = (nn[j] + h1[1][j]) + (w0 + e0);
            float l0 = fmaf(-4.f, h1[0][j], sum0);
            h2[0][j] = fmaf(cf[0][j], l0, fmaf(2.f, h1[0][j], -h2[0][j]));

            float w1 = (j > 0) ? h1[1][j-1] : ww1;
            float e1 = (j < 7) ? h1[1][j+1] : ee1;
            float sum1 = (h1[0][j] + ss[j]) + (w1 + e1);
            float l1 = fmaf(-4.f, h1[1][j], sum1);
            h2[1][j] = fmaf(cf[1][j], l1, fmaf(2.f, h1[1][j], -h2[1][j]));
        }

        if (src_r0 | src_r1) {
            float v = DT2 * wav[t];
#pragma unroll
            for (int j = 0; j < 8; ++j) if (j == sj) {
                if (src_r0) h2[0][j] += v;
                if (src_r1) h2[1][j] += v;
            }
        }

        if (rcnt > 0) { float v = (rt0 & 8) ? select8(h2[1], rt0 & 7) : select8(h2[0], rt0 & 7);
                        outb[t*NREC_ + (rt0 >> 4)] = v; }
        if (rcnt > 1) { float v = (rt1 & 8) ? select8(h2[1], rt1 & 7) : select8(h2[0], rt1 & 7);
                        outb[t*NREC_ + (rt1 >> 4)] = v; }
        if (rcnt > 2) { float v = (rt2 & 8) ? select8(h2[1], rt2 & 7) : select8(h2[0], rt2 & 7);
                        outb[t*NREC_ + (rt2 >> 4)] = v; }
        if (rcnt > 3) { float v = (rt3 & 8) ? select8(h2[1], rt3 & 7) : select8(h2[0], rt3 & 7);
                        outb[t*NREC_ + (rt3 >> 4)] = v; }

        __syncthreads();   // protect pub (WAR) for next step
    };

    // ghost exchange after round e: cur/prev are the latest two time levels.
    // Plain cached stores/loads; grid.sync() provides cross-block visibility.
    // Double-buffered by round parity (a fast block's round-e+1 writes must
    // not collide with a slow block's round-e reads).
    auto exchange = [&](float (&cur)[2][8], float (&prev)[2][8], int e) {
        const int buf = e & 1;
        if (ty >= 8 && ty < 24) {          // publish interior boundary slabs
            int side = (ty < 16) ? 0 : 1;
            int sr0 = 2 * ty - (side ? 32 : 16);
            float* d0 = gslab(blk, side, 0, buf) + gc0;
            float* d1 = gslab(blk, side, 1, buf) + gc0;
            *(float4*)&d0[sr0*NX_]     = make_float4(cur[0][0],cur[0][1],cur[0][2],cur[0][3]);
            *(float4*)&d0[sr0*NX_+4]   = make_float4(cur[0][4],cur[0][5],cur[0][6],cur[0][7]);
            *(float4*)&d0[(sr0+1)*NX_]   = make_float4(cur[1][0],cur[1][1],cur[1][2],cur[1][3]);
            *(float4*)&d0[(sr0+1)*NX_+4] = make_float4(cur[1][4],cur[1][5],cur[1][6],cur[1][7]);
            *(float4*)&d1[sr0*NX_]     = make_float4(prev[0][0],prev[0][1],prev[0][2],prev[0][3]);
            *(float4*)&d1[sr0*NX_+4]   = make_float4(prev[0][4],prev[0][5],prev[0][6],prev[0][7]);
            *(float4*)&d1[(sr0+1)*NX_]   = make_float4(prev[1][0],prev[1][1],prev[1][2],prev[1][3]);
            *(float4*)&d1[(sr0+1)*NX_+4] = make_float4(prev[1][4],prev[1][5],prev[1][6],prev[1][7]);
        }
        grid.sync();                       // all slabs visible device-wide
        if (ty < 8 && p > 0) {             // refill top ghost from north neighbor
            int sr0 = 2 * ty;
            const float* s0 = gslab(blk-1, 1, 0, buf) + gc0;
            const float* s1 = gslab(blk-1, 1, 1, buf) + gc0;
            float4 a0 = *(const float4*)&s0[sr0*NX_];
            float4 a1 = *(const float4*)&s0[sr0*NX_+4];
            float4 a2 = *(const float4*)&s0[(sr0+1)*NX_];
            float4 a3 = *(const float4*)&s0[(sr0+1)*NX_+4];
            float4 b0 = *(const float4*)&s1[sr0*NX_];
            float4 b1 = *(const float4*)&s1[sr0*NX_+4];
            float4 b2 = *(const float4*)&s1[(sr0+1)*NX_];
            float4 b3 = *(const float4*)&s1[(sr0+1)*NX_+4];
            cur[0][0]=a0.x; cur[0][1]=a0.y; cur[0][2]=a0.z; cur[0][3]=a0.w;
            cur[0][4]=a1.x; cur[0][5]=a1.y; cur[0][6]=a1.z; cur[0][7]=a1.w;
            cur[1][0]=a2.x; cur[1][1]=a2.y; cur[1][2]=a2.z; cur[1][3]=a2.w;
            cur[1][4]=a3.x; cur[1][5]=a3.y; cur[1][6]=a3.z; cur[1][7]=a3.w;
            prev[0][0]=b0.x; prev[0][1]=b0.y; prev[0][2]=b0.z; prev[0][3]=b0.w;
            prev[0][4]=b1.x; prev[0][5]=b1.y; prev[0][6]=b1.z; prev[0][7]=b1.w;
            prev[1][0]=b2.x; prev[1][1]=b2.y; prev[1][2]=b2.z; prev[1][3]=b2.w;
            prev[1][4]=b3.x; prev[1][5]=b3.y; prev[1][6]=b3.z; prev[1][7]=b3.w;
        }
        if (ty >= 24 && p < PIECES-1) {    // refill bottom ghost from south
            int sr0 = 2 * ty - 48;
            const float* s0 = gslab(blk+1, 0, 0, buf) + gc0;
            const float* s1 = gslab(blk+1, 0, 1, buf) + gc0;
            float4 a0 = *(const float4*)&s0[sr0*NX_];
            float4 a1 = *(const float4*)&s0[sr0*NX_+4];
            float4 a2 = *(const float4*)&s0[(sr0+1)*NX_];
            float4 a3 = *(const float4*)&s0[(sr0+1)*NX_+4];
            float4 b0 = *(const float4*)&s1[sr0*NX_];
            float4 b1 = *(const float4*)&s1[sr0*NX_+4];
            float4 b2 = *(const float4*)&s1[(sr0+1)*NX_];
            float4 b3 = *(const float4*)&s1[(sr0+1)*NX_+4];
            cur[0][0]=a0.x; cur[0][1]=a0.y; cur[0][2]=a0.z; cur[0][3]=a0.w;
            cur[0][4]=a1.x; cur[0][5]=a1.y; cur[0][6]=a1.z; cur[0][7]=a1.w;
            cur[1][0]=a2.x; cur[1][1]=a2.y; cur[1][2]=a2.z; cur[1][3]=a2.w;
            cur[1][4]=a3.x; cur[1][5]=a3.y; cur[1][6]=a3.z; cur[1][7]=a3.w;
            prev[0][0]=b0.x; prev[0][1]=b0.y; prev[0][2]=b0.z; prev[0][3]=b0.w;
            prev[0][4]=b1.x; prev[0][5]=b1.y; prev[0][6]=b1.z; prev[0][7]=b1.w;
            prev[1][0]=b2.x; prev[1][1]=b2.y; prev[1][2]=b2.z; prev[1][3]=b2.w;
            prev[1][4]=b3.x; prev[1][5]=b3.y; prev[1][6]=b3.z; prev[1][7]=b3.w;
        }
    };

    int t = 0;
#pragma unroll 1
    for (int e = 0; e < ROUNDS; ++e) {
#pragma unroll 1
        for (int s = 0; s < G; s += 2) {
            step(hA, hB, t);
            step(hB, hA, t + 1);
            t += 2;
        }
        // after 16 steps: hA = current, hB = previous
        if (e < ROUNDS - 1) exchange(hA, hB, e);
    }
}

extern "C" void kernel_launch(void* const* d_in, const int* in_sizes, int n_in,
                              void* d_out, int out_size, void* d_ws, size_t ws_size,
                              hipStream_t stream) {
    const float* x   = (const float*)d_in[0];
    const float* vp  = (const float*)d_in[1];
    const int*   src = (const int*)d_in[2];
    const int*   rec = (const int*)d_in[3];
    float*       o   = (float*)d_out;
    float*       gbuf = (float*)d_ws;   // fully written before read each round
    void* args[] = { (void*)&x, (void*)&vp, (void*)&src, (void*)&rec,
                     (void*)&o, (void*)&gbuf };
    hipLaunchCooperativeKernel((void*)wave_tb_kernel, dim3(B_ * PIECES),
                               dim3(1024), args, 0, stream);
}

// Round 6
// 440.133 us; speedup vs baseline: 5.3223x; 4.9609x over previous
//
#include <hip/hip_runtime.h>

typedef float v4f __attribute__((ext_vector_type(4)));

namespace {
constexpr int B_     = 8;
constexpr int NT_    = 256;
constexpr int NX_    = 256;
constexpr int NREC_  = 64;
constexpr int PIECES = 8;              // vertical strips per batch
constexpr int IROWS  = 32;             // interior rows per strip
constexpr int G      = 16;             // ghost width = steps per round
constexpr int ROUNDS = NT_ / G;        // 16
constexpr float DT2  = 1e-6f;          // DT*DT
constexpr float KLAP = 1e-8f;          // DT*DT/(DH*DH)
constexpr size_t FLAGS_BYTES = 4096;
} // namespace

// 64 blocks: piece p of batch b (blockIdx = p*8 + b: pieces of a batch share an
// XCD under round-robin dispatch — perf heuristic only; correctness rests on
// agent-scope fences/flags). Each block evolves 64 ext rows (32 interior + 16
// ghost each side); exchange every G=16 steps.
//
// R4 lesson: per-thread register-resident field state (2 rows/thread) spills to
// scratch (VGPR_Count=64 < live set) and scratch round-trips drained at every
// barrier cost ~8 us/step. Fix: BOTH time levels live in LDS (2x66x256 fp32 =
// 132 KB of the 160 KB/CU); threads keep no persistent field state (~50 VGPR).
// Lane l <-> cols 4l..4l+3: every LDS access is a full-row b128, conflict-free
// (one wave = one 4-row band). One barrier per step. Horizontal halo via shfl.
extern "C" __global__ __launch_bounds__(1024, 4)
void wave_lds_kernel(const float* __restrict__ x,
                     const float* __restrict__ vp,
                     const int* __restrict__ src_loc,
                     const int* __restrict__ rec_loc,
                     float* __restrict__ out,
                     int* __restrict__ flags,   // [64] monotone round counters
                     float* __restrict__ gbuf)  // [par2][64][side2][lvl2][16][256]
{
    __shared__ float lev[2][66][256];  // 132 KB: rows 0 and 65 are zero pads
    __shared__ float wav[NT_];         // 1 KB wavelet

    const int bid  = blockIdx.x;
    const int b    = bid & 7;
    const int p    = bid >> 3;
    const int blk  = b * PIECES + p;
    const int tid  = threadIdx.x;
    const int band = tid >> 6;             // wave id 0..15 -> 4 ext rows
    const int lane = tid & 63;
    const int er0  = band << 2;            // first owned ext row (0..60)
    const int c0   = lane << 2;            // first owned col (0..252)
    const int grt  = p * IROWS - G + er0;  // global row of owned row 0

    // zero both LDS levels (incl. pad rows)
    {
        v4f z = {0.f, 0.f, 0.f, 0.f};
        for (int i = tid; i < 2 * 66 * 256 / 4; i += 1024) ((v4f*)lev)[i] = z;
    }
    if (tid < NT_) wav[tid] = x[b * NT_ + tid];

    // cf = vp^2*DT^2/DH^2, zeroed at Dirichlet boundary + out-of-domain rows
    v4f cf4[4];
#pragma unroll
    for (int i = 0; i < 4; ++i) {
        int gr = grt + i;
        int crow = gr < 0 ? 0 : (gr > 255 ? 255 : gr);
        bool rowok = (gr >= 1) && (gr <= 254);
        v4f vv = *(const v4f*)&vp[crow * NX_ + c0];
        float cc[4];
#pragma unroll
        for (int k = 0; k < 4; ++k) {
            int col = c0 + k;
            float vk = (k == 0) ? vv.x : (k == 1) ? vv.y : (k == 2) ? vv.z : vv.w;
            cc[k] = (rowok && col >= 1 && col <= 254) ? vk * vk * KLAP : 0.f;
        }
        cf4[i].x = cc[0]; cf4[i].y = cc[1]; cf4[i].z = cc[2]; cf4[i].w = cc[3];
    }

    // source ownership (ghost rows included: ghost evolution must replay it)
    const int sz = src_loc[b * 2 + 0], sx = src_loc[b * 2 + 1];
    const int si = sz - grt;               // 0..3 if owned row
    const int sj = sx - c0;                // 0..3 if owned col
    const bool has_src = ((unsigned)si < 4u) && ((unsigned)sj < 4u);

    // receiver ownership: thread r (<64) of the block whose INTERIOR holds it
    bool rown = false; int rrow = 1, rcol = 0;
    if (tid < NREC_) {
        int rz = rec_loc[(b * NREC_ + tid) * 2 + 0];
        int rx = rec_loc[(b * NREC_ + tid) * 2 + 1];
        if (rz >= p * IROWS && rz < p * IROWS + IROWS) {
            rown = true; rrow = rz - (p * IROWS - G) + 1; rcol = rx;
        }
    }
    float* outb = out + (size_t)b * NT_ * NREC_ + tid;

    __syncthreads();

    // one leapfrog step; cu is compile-time 0/1 in the unrolled pair below.
    // Streamed over the 4 owned rows to keep live VGPRs ~50 (no spill).
    auto step = [&](int t, int cu) {
        const int pv = cu ^ 1;
        const float sv = DT2 * wav[t];
        v4f r0 = *(const v4f*)&lev[cu][er0 + 0][c0];   // ext row er0-1 (pad-safe)
        v4f r1 = *(const v4f*)&lev[cu][er0 + 1][c0];   // ext row er0
#pragma unroll
        for (int i = 0; i < 4; ++i) {
            v4f r2 = *(const v4f*)&lev[cu][er0 + 2 + i][c0];  // south row
            v4f pz = *(const v4f*)&lev[pv][er0 + 1 + i][c0];  // prev center
            float wv = __shfl_up(r1.w, 1, 64);   // col c0-1 (garbage at lane 0: cf=0 there)
            float ev = __shfl_down(r1.x, 1, 64); // col c0+4
            v4f hn;
            { float s = (r0.x + r2.x) + (wv   + r1.y);
              hn.x = fmaf(cf4[i].x, fmaf(-4.f, r1.x, s), fmaf(2.f, r1.x, -pz.x)); }
            { float s = (r0.y + r2.y) + (r1.x + r1.z);
              hn.y = fmaf(cf4[i].y, fmaf(-4.f, r1.y, s), fmaf(2.f, r1.y, -pz.y)); }
            { float s = (r0.z + r2.z) + (r1.y + r1.w);
              hn.z = fmaf(cf4[i].z, fmaf(-4.f, r1.z, s), fmaf(2.f, r1.z, -pz.z)); }
            { float s = (r0.w + r2.w) + (r1.z + ev  );
              hn.w = fmaf(cf4[i].w, fmaf(-4.f, r1.w, s), fmaf(2.f, r1.w, -pz.w)); }
            if (has_src && si == i) {
                if      (sj == 0) hn.x += sv;
                else if (sj == 1) hn.y += sv;
                else if (sj == 2) hn.z += sv;
                else              hn.w += sv;
            }
            *(v4f*)&lev[pv][er0 + 1 + i][c0] = hn;
            r0 = r1; r1 = r2;
        }
        __syncthreads();   // new level complete; next step reads it as cur
        // receiver gather of the NEW level (no race: next step writes lev[cu])
        if (rown) outb[t * NREC_] = lev[pv][rrow][rcol];
    };

    // ghost exchange after round e. Plain cached coalesced slab stores/loads;
    // agent-scope release-fence + flag / acquire-fence (R2/R3-proven protocol).
    // Slabs parity double-buffered (neighbors may be one round apart).
    auto exchange = [&](int e) {
        const int par = e & 1;
#pragma unroll
        for (int k = 0; k < 4; ++k) {      // publish interior halves, both levels
            int f = k * 1024 + tid;        // 0..4095 float4s
            int side = f >> 11, lvl = (f >> 10) & 1, rr = (f >> 6) & 15;
            int cq = (f & 63) << 2;
            int srow = (side ? 33 : 17) + rr;   // er 32..47 / er 16..31
            v4f v = *(const v4f*)&lev[lvl][srow][cq];
            size_t gi = ((((((size_t)par * 64 + blk) * 2 + side) * 2 + lvl) * 16 + rr) * 256) + cq;
            *(v4f*)&gbuf[gi] = v;
        }
        __syncthreads();                   // all waves' stores vmcnt-drained
        if (tid == 0) {
            __builtin_amdgcn_fence(__ATOMIC_RELEASE, "agent");
            __hip_atomic_store(&flags[blk], e + 1, __ATOMIC_RELEASE,
                               __HIP_MEMORY_SCOPE_AGENT);
            if (p > 0)
                while (__hip_atomic_load(&flags[blk - 1], __ATOMIC_ACQUIRE,
                                         __HIP_MEMORY_SCOPE_AGENT) < e + 1)
                    __builtin_amdgcn_s_sleep(8);
            __builtin_amdgcn_fence(__ATOMIC_ACQUIRE, "agent");
        }
        if (tid == 64 && p < PIECES - 1) { // second wave polls south in parallel
            while (__hip_atomic_load(&flags[blk + 1], __ATOMIC_ACQUIRE,
                                     __HIP_MEMORY_SCOPE_AGENT) < e + 1)
                __builtin_amdgcn_s_sleep(8);
            __builtin_amdgcn_fence(__ATOMIC_ACQUIRE, "agent");
        }
        __syncthreads();                   // fences ordered before all reads
#pragma unroll
        for (int k = 0; k < 4; ++k) {      // refill ghosts from neighbor slabs
            int f = k * 1024 + tid;
            int side = f >> 11, lvl = (f >> 10) & 1, rr = (f >> 6) & 15;
            int cq = (f & 63) << 2;
            bool ok = side ? (p < PIECES - 1) : (p > 0);
            if (ok) {
                int nb  = side ? blk + 1 : blk - 1;
                int nsd = side ^ 1;
                size_t gi = ((((((size_t)par * 64 + nb) * 2 + nsd) * 2 + lvl) * 16 + rr) * 256) + cq;
                v4f v = *(const v4f*)&gbuf[gi];
                int drow = (side ? 49 : 1) + rr;   // bottom ghosts / top ghosts
                *(v4f*)&lev[lvl][drow][cq] = v;
            }
        }
        __syncthreads();                   // ghosts in LDS before next round
    };

    int t = 0;
#pragma unroll 1
    for (int e = 0; e < ROUNDS; ++e) {
#pragma unroll 1
        for (int s = 0; s < G; s += 2) {
            step(t, 0);        // t even -> cur = lev[0]
            step(t + 1, 1);
            t += 2;
        }
        if (e < ROUNDS - 1) exchange(e);
    }
}

extern "C" void kernel_launch(void* const* d_in, const int* in_sizes, int n_in,
                              void* d_out, int out_size, void* d_ws, size_t ws_size,
                              hipStream_t stream) {
    const float* x   = (const float*)d_in[0];
    const float* vp  = (const float*)d_in[1];
    const int*   src = (const int*)d_in[2];
    const int*   rec = (const int*)d_in[3];
    float*       o   = (float*)d_out;
    int*   flags = (int*)d_ws;
    float* gbuf  = (float*)((char*)d_ws + FLAGS_BYTES);
    (void)hipMemsetAsync(d_ws, 0, FLAGS_BYTES, stream);   // flags must start at 0
    hipLaunchKernelGGL(wave_lds_kernel, dim3(B_ * PIECES), dim3(1024), 0, stream,
                       x, vp, src, rec, o, flags, gbuf);
}

// Round 7
// 399.320 us; speedup vs baseline: 5.8663x; 1.1022x over previous
//
#include <hip/hip_runtime.h>

typedef float v4f __attribute__((ext_vector_type(4)));

namespace {
constexpr int B_     = 8;
constexpr int NT_    = 256;
constexpr int NX_    = 256;
constexpr int NREC_  = 64;
constexpr int PIECES = 8;              // vertical strips per batch
constexpr int IROWS  = 32;             // interior rows per strip
constexpr int G      = 16;             // ghost width = steps per round
constexpr int ROUNDS = NT_ / G;        // 16
constexpr float DT2  = 1e-6f;          // DT*DT
constexpr float KLAP = 1e-8f;          // DT*DT/(DH*DH)
constexpr size_t FLAGS_BYTES = 4096;
constexpr int RCAP = 6;
} // namespace

// 64 blocks: piece p of batch b (blockIdx = p*8 + b). Each block evolves 64 ext
// rows (32 interior + 16 ghost each side); cross-block exchange every G=16
// steps via cached slabs + agent-scope flag handshake (R6-proven).
//
// R6 lesson: full-LDS state is LDS-throughput-bound (~14 b128 ops/thread/step).
// R7: thread's own 4x4 tile of BOTH levels lives in REGISTERS (A,B: 32 VGPR);
// LDS holds only band-boundary halo rows (publish row0/row3, read 2 halo rows)
// -> ~6 b128-class LDS ops/thread/step. prev level needs no LDS at all.
// waves_per_eu(4,4) pins the VGPR budget at 128 so the compiler cannot repeat
// R4's spill-for-occupancy heuristic. One barrier/step (halo pub is parity
// double-buffered to kill the WAR hazard).
extern "C" __global__
__attribute__((amdgpu_flat_work_group_size(1024, 1024), amdgpu_waves_per_eu(4, 4)))
void wave_reg_kernel(const float* __restrict__ x,
                     const float* __restrict__ vp,
                     const int* __restrict__ src_loc,
                     const int* __restrict__ rec_loc,
                     float* __restrict__ out,
                     int* __restrict__ flags,   // [64] monotone round counters
                     float* __restrict__ gbuf)  // [par2][64][side2][lvl2][16][256]
{
    __shared__ float pub[2][2][16][256];  // 64 KB: [par][top/bot row][band][col]
    __shared__ float wav[NT_];            // 1 KB wavelet

    const int bid  = blockIdx.x;
    const int b    = bid & 7;
    const int p    = bid >> 3;
    const int blk  = b * PIECES + p;
    const int tid  = threadIdx.x;
    const int band = tid >> 6;             // wave id 0..15 -> 4 ext rows
    const int lane = tid & 63;
    const int c0   = lane << 2;            // first owned col (0..252)
    const int grt  = p * IROWS - G + (band << 2);  // global row of owned row 0

    if (tid < NT_) wav[tid] = x[b * NT_ + tid];

    // cf = vp^2*DT^2/DH^2, zeroed at Dirichlet boundary + out-of-domain rows
    v4f cf[4];
#pragma unroll
    for (int i = 0; i < 4; ++i) {
        int gr = grt + i;
        int crow = gr < 0 ? 0 : (gr > 255 ? 255 : gr);
        bool rowok = (gr >= 1) && (gr <= 254);
        v4f vv = *(const v4f*)&vp[crow * NX_ + c0];
        float cc[4];
#pragma unroll
        for (int k = 0; k < 4; ++k) {
            int col = c0 + k;
            float vk = (k == 0) ? vv.x : (k == 1) ? vv.y : (k == 2) ? vv.z : vv.w;
            cc[k] = (rowok && col >= 1 && col <= 254) ? vk * vk * KLAP : 0.f;
        }
        cf[i].x = cc[0]; cf[i].y = cc[1]; cf[i].z = cc[2]; cf[i].w = cc[3];
    }

    // source ownership (ghost rows included: ghost evolution must replay it)
    const int sz = src_loc[b * 2 + 0], sx = src_loc[b * 2 + 1];
    const int si = sz - grt;               // 0..3 if owned row
    const int sj = sx - c0;                // 0..3 if owned col
    const bool has_src = ((unsigned)si < 4u) && ((unsigned)sj < 4u);

    // receiver slots: interior owner only (unique writer). pk=(r<<4)|(i<<2)|j
    int rs[RCAP]; int rcnt = 0;
#pragma unroll 1
    for (int r = 0; r < NREC_; ++r) {
        int rz = rec_loc[(b * NREC_ + r) * 2 + 0];
        int rx = rec_loc[(b * NREC_ + r) * 2 + 1];
        int i = rz - grt, j = rx - c0;
        if (rz >= p * IROWS && rz < p * IROWS + IROWS &&
            (unsigned)i < 4u && (unsigned)j < 4u) {
            if (rcnt < RCAP) rs[rcnt] = (r << 4) | (i << 2) | j;
            ++rcnt;
        }
    }
    if (rcnt > RCAP) rcnt = RCAP;
    float* outb = out + (size_t)b * NT_ * NREC_;

    v4f A[4], B[4];
    {
        v4f z = {0.f, 0.f, 0.f, 0.f};
#pragma unroll
        for (int i = 0; i < 4; ++i) { A[i] = z; B[i] = z; }
    }

    // one step: P <- update(C, P); P becomes current. par = t&1.
    auto step = [&](v4f (&C)[4], v4f (&P)[4], int t, int par) {
        *(v4f*)&pub[par][0][band][c0] = C[0];   // my top row (south halo of band-1)
        *(v4f*)&pub[par][1][band][c0] = C[3];   // my bottom row (north halo of band+1)
        __syncthreads();
        v4f nn, ss;
        if (band > 0)  nn = *(const v4f*)&pub[par][1][band - 1][c0];
        else           { nn.x = 0.f; nn.y = 0.f; nn.z = 0.f; nn.w = 0.f; }
        if (band < 15) ss = *(const v4f*)&pub[par][0][band + 1][c0];
        else           { ss.x = 0.f; ss.y = 0.f; ss.z = 0.f; ss.w = 0.f; }
        const float sv = DT2 * wav[t];
#pragma unroll
        for (int i = 0; i < 4; ++i) {
            v4f n = (i == 0) ? nn : C[i - 1];
            v4f s = (i == 3) ? ss : C[i + 1];
            float wv = __shfl_up(C[i].w, 1, 64);   // col c0-1 (lane0 garbage: cf=0)
            float ev = __shfl_down(C[i].x, 1, 64); // col c0+4 (lane63 garbage: cf=0)
            v4f hn;
            { float sm = (n.x + s.x) + (wv     + C[i].y);
              hn.x = fmaf(cf[i].x, fmaf(-4.f, C[i].x, sm), fmaf(2.f, C[i].x, -P[i].x)); }
            { float sm = (n.y + s.y) + (C[i].x + C[i].z);
              hn.y = fmaf(cf[i].y, fmaf(-4.f, C[i].y, sm), fmaf(2.f, C[i].y, -P[i].y)); }
            { float sm = (n.z + s.z) + (C[i].y + C[i].w);
              hn.z = fmaf(cf[i].z, fmaf(-4.f, C[i].z, sm), fmaf(2.f, C[i].z, -P[i].z)); }
            { float sm = (n.w + s.w) + (C[i].z + ev);
              hn.w = fmaf(cf[i].w, fmaf(-4.f, C[i].w, sm), fmaf(2.f, C[i].w, -P[i].w)); }
            if (has_src && si == i) {
                if      (sj == 0) hn.x += sv;
                else if (sj == 1) hn.y += sv;
                else if (sj == 2) hn.z += sv;
                else              hn.w += sv;
            }
            P[i] = hn;
        }
        // receiver gather from the NEW level (registers)
#pragma unroll
        for (int k = 0; k < RCAP; ++k) {
            if (rcnt > k) {
                int pk = rs[k];
                int i = (pk >> 2) & 3, j = pk & 3, r = pk >> 4;
                v4f t01 = (i & 1) ? P[1] : P[0];
                v4f t23 = (i & 1) ? P[3] : P[2];
                v4f rw  = (i & 2) ? t23 : t01;
                float c01 = (j & 1) ? rw.y : rw.x;
                float c23 = (j & 1) ? rw.w : rw.z;
                outb[t * NREC_ + r] = (j & 2) ? c23 : c01;
            }
        }
        // no trailing barrier: next step uses pub[par^1] (parity double-buffer)
    };

    // ghost exchange after round e: A=cur(lvl0), B=prev(lvl1), regs <-> global
    auto exchange = [&](int e) {
        auto gptr = [&](int bk, int side, int lvl, int rr) -> float* {
            return gbuf + (((((size_t)(e & 1) * 64 + bk) * 2 + side) * 2 + lvl)
                           * 16 + rr) * 256;
        };
        if (band >= 4 && band < 12) {      // publish interior halves, both levels
            int side = (band >= 8) ? 1 : 0;
            int rr0 = (band << 2) - (side ? 32 : 16);
#pragma unroll
            for (int i = 0; i < 4; ++i) {
                *(v4f*)&gptr(blk, side, 0, rr0 + i)[c0] = A[i];
                *(v4f*)&gptr(blk, side, 1, rr0 + i)[c0] = B[i];
            }
        }
        __syncthreads();                   // every wave's stores vmcnt-drained
        if (tid == 0) {
            __builtin_amdgcn_fence(__ATOMIC_RELEASE, "agent");
            __hip_atomic_store(&flags[blk], e + 1, __ATOMIC_RELEASE,
                               __HIP_MEMORY_SCOPE_AGENT);
            if (p > 0)
                while (__hip_atomic_load(&flags[blk - 1], __ATOMIC_ACQUIRE,
                                         __HIP_MEMORY_SCOPE_AGENT) < e + 1)
                    __builtin_amdgcn_s_sleep(8);
            __builtin_amdgcn_fence(__ATOMIC_ACQUIRE, "agent");
        }
        if (tid == 64 && p < PIECES - 1) { // second wave polls south in parallel
            while (__hip_atomic_load(&flags[blk + 1], __ATOMIC_ACQUIRE,
                                     __HIP_MEMORY_SCOPE_AGENT) < e + 1)
                __builtin_amdgcn_s_sleep(8);
            __builtin_amdgcn_fence(__ATOMIC_ACQUIRE, "agent");
        }
        __syncthreads();                   // all threads ordered after acquire
        if (band < 4 && p > 0) {           // refill top ghost from north neighbor
            int rr0 = band << 2;
#pragma unroll
            for (int i = 0; i < 4; ++i) {
                A[i] = *(const v4f*)&gptr(blk - 1, 1, 0, rr0 + i)[c0];
                B[i] = *(const v4f*)&gptr(blk - 1, 1, 1, rr0 + i)[c0];
            }
        }
        if (band >= 12 && p < PIECES - 1) {  // refill bottom ghost from south
            int rr0 = (band << 2) - 48;
#pragma unroll
            for (int i = 0; i < 4; ++i) {
                A[i] = *(const v4f*)&gptr(blk + 1, 0, 0, rr0 + i)[c0];
                B[i] = *(const v4f*)&gptr(blk + 1, 0, 1, rr0 + i)[c0];
            }
        }
    };

    int t = 0;
#pragma unroll 1
    for (int e = 0; e < ROUNDS; ++e) {
#pragma unroll 1
        for (int s = 0; s < G; s += 2) {
            step(A, B, t, 0);      // t even: cur=A, par=0
            step(B, A, t + 1, 1);  // t odd:  cur=B, par=1
            t += 2;
        }
        // after 16 steps: A = current level, B = previous level
        if (e < ROUNDS - 1) exchange(e);
    }
}

extern "C" void kernel_launch(void* const* d_in, const int* in_sizes, int n_in,
                              void* d_out, int out_size, void* d_ws, size_t ws_size,
                              hipStream_t stream) {
    const float* x   = (const float*)d_in[0];
    const float* vp  = (const float*)d_in[1];
    const int*   src = (const int*)d_in[2];
    const int*   rec = (const int*)d_in[3];
    float*       o   = (float*)d_out;
    int*   flags = (int*)d_ws;
    float* gbuf  = (float*)((char*)d_ws + FLAGS_BYTES);
    (void)hipMemsetAsync(d_ws, 0, FLAGS_BYTES, stream);   // flags must start at 0
    hipLaunchKernelGGL(wave_reg_kernel, dim3(B_ * PIECES), dim3(1024), 0, stream,
                       x, vp, src, rec, o, flags, gbuf);
}